// Round 5
// baseline (263.484 us; speedup 1.0000x reference)
//
#include <hip/hip_runtime.h>
#include <hip/hip_bf16.h>

typedef __bf16 bf16_t;
typedef __attribute__((ext_vector_type(8))) __bf16 bf16x8;
typedef __attribute__((ext_vector_type(4))) float f32x4;

#define N1 16384
#define N2 4096
#define C1 128
#define C2 256
#define CIN 384
#define HD1 256
#define HD2 128
#define BDIM 4
#define CHUNK 512
#define NCHUNK 8   // N2 / CHUNK
#define NCAND 24   // NCHUNK * 3

// ---- prep: W1/W2 -> bf16 [N][K]; f2 -> bf16 (validated R4 bodies) ----
__global__ void prep_w(const float* __restrict__ W1, const float* __restrict__ W2,
                       const float* __restrict__ f2,
                       bf16_t* __restrict__ W1t, bf16_t* __restrict__ W2t,
                       bf16_t* __restrict__ f2bf) {
  int tid = blockIdx.x * 256 + threadIdx.x;
  if (tid < CIN * HD1) {
    int k = tid / HD1, n = tid % HD1;
    W1t[n * CIN + k] = (bf16_t)W1[tid];
  }
  if (tid < HD1 * HD2) {
    int k = tid / HD2, n = tid % HD2;
    W2t[n * HD1 + k] = (bf16_t)W2[tid];
  }
  const float4* s4 = (const float4*)f2;
  float4 a = s4[2 * (size_t)tid], b = s4[2 * (size_t)tid + 1];
  bf16x8 o;
  o[0] = (bf16_t)a.x; o[1] = (bf16_t)a.y; o[2] = (bf16_t)a.z; o[3] = (bf16_t)a.w;
  o[4] = (bf16_t)b.x; o[5] = (bf16_t)b.y; o[6] = (bf16_t)b.z; o[7] = (bf16_t)b.w;
  *(bf16x8*)(f2bf + (size_t)tid * 8) = o;
}

// ---- per-chunk top-3 (VALIDATED 99.4us kernel, verbatim) ----
__global__ __launch_bounds__(256) void knn_chunk(
    const float* __restrict__ xyz1, const float* __restrict__ xyz2,
    float* __restrict__ candd, int* __restrict__ candj) {
  int b  = blockIdx.y;
  int ck = blockIdx.z;
  int i  = blockIdx.x * 256 + threadIdx.x;
  const float* p = xyz1 + ((size_t)b * N1 + i) * 3;
  float px = p[0], py = p[1], pz = p[2];

  const float* x2b = xyz2 + ((size_t)b * N2 + (size_t)ck * CHUNK) * 3;

  float d0 = 3.4e38f, d1 = 3.4e38f, d2 = 3.4e38f;
  int   j0 = 0, j1 = 0, j2 = 0;

  for (int j = 0; j < CHUNK; j += 16) {
    float c[48];
    const float4* q = (const float4*)(x2b + 3 * j);
#pragma unroll
    for (int t = 0; t < 12; ++t) {
      float4 v = q[t];
      c[4 * t + 0] = v.x; c[4 * t + 1] = v.y; c[4 * t + 2] = v.z; c[4 * t + 3] = v.w;
    }
#pragma unroll
    for (int u = 0; u < 16; ++u) {
      float dx = __fsub_rn(c[3 * u + 0], px);
      float dy = __fsub_rn(c[3 * u + 1], py);
      float dz = __fsub_rn(c[3 * u + 2], pz);
      float d = __fadd_rn(__fadd_rn(__fmul_rn(dx, dx), __fmul_rn(dy, dy)),
                          __fmul_rn(dz, dz));
      int jj = j + u;
      if (d < d2) {  // strict <: earlier index wins ties (matches top_k)
        bool lt0 = d < d0, lt1 = d < d1;
        j2 = lt1 ? j1 : jj;
        j1 = lt0 ? j0 : (lt1 ? jj : j1);
        j0 = lt0 ? jj : j0;
        d2 = __builtin_amdgcn_fmed3f(d, d1, d2);
        d1 = __builtin_amdgcn_fmed3f(d, d0, d1);
        d0 = fminf(d, d0);
      }
    }
  }
  size_t qb = ((size_t)b * N1 + i) * NCAND + (size_t)ck * 3;
  int jbase = ck * CHUNK;
  candd[qb + 0] = d0; candd[qb + 1] = d1; candd[qb + 2] = d2;
  candj[qb + 0] = j0 + jbase; candj[qb + 1] = j1 + jbase; candj[qb + 2] = j2 + jbase;
}

// ---- FUSED tail: merge + interp + concat + GEMM1 + GEMM2 -> out ----
// 1024 blocks x 64 rows. Phase 1 (validated R4 structure, 64x256 tile):
// A-tile computed into LDS (3-NN bf16 gather ks<8, f1 cast ks>=8), W1 staged
// via global_load_lds (verbatim pattern), 4 waves split N (wn = wv*64),
// acc[4][4]/wave. H = relu(.+b1) -> bf16 -> LDS Hs[64][256] with the G4
// XOR swizzle (byte ^= (row&7)<<4): row stride 512B would be a 16-way bank
// conflict on phase-2 ds_read_b128; swizzle makes it 2-way (free).
// Phase 2: out[64][128] = relu(Hs @ W2t^T + b2); K=256 in 8 steps; W2 staged
// like W1; wave wv computes rows wv*16..+15, acc2[8]. All fragment mappings
// verbatim from validated kernels -> output bit-identical to R4.
// LDS 52 KB -> 3 blocks/CU (12 waves/CU, better latency hiding than R4's 8).
__global__ __launch_bounds__(256, 3) void fused_tail(
    const float* __restrict__ f1, const bf16_t* __restrict__ f2b_,
    const float* __restrict__ candd, const int* __restrict__ candj,
    const bf16_t* __restrict__ W1t, const float* __restrict__ b1,
    const bf16_t* __restrict__ W2t, const float* __restrict__ b2,
    float* __restrict__ out) {
  __shared__ __align__(16) char smem[53248];          // 52 KB
  bf16_t* As  = (bf16_t*)smem;                        // 4 KB  [64][32]
  bf16_t* Bs  = (bf16_t*)(smem + 4096);               // 16 KB [koct][256][8]
  bf16_t* Bs2 = (bf16_t*)smem;                        // 8 KB  (phase2) [koct][128][8]
  char*   hs  = smem + 20480;                         // 32 KB Hs[64][256] swizzled
  float*  mw  = (float*)(smem + 20480);               // transient (dead before Hs)
  int*    mj  = (int*)(smem + 20480 + 768);

  int tid = threadIdx.x;
  int wv = tid >> 6, ln = tid & 63, quad = ln >> 4, lm = ln & 15;
  long row0 = (long)blockIdx.x * 64;

  // ---- merge 8x3 candidates per row (validated knn_merge body) ----
  if (tid < 64) {
    size_t q = row0 + tid;
    const float* cd = candd + q * NCAND;
    const int*   cj = candj + q * NCAND;
    float d0 = 3.4e38f, d1 = 3.4e38f, d2 = 3.4e38f;
    int   j0 = 0, j1 = 0, j2 = 0;
#pragma unroll
    for (int c = 0; c < NCAND; ++c) {
      float d = cd[c]; int j = cj[c];
      bool p0 = d < d0, p1 = d < d1, p2 = d < d2;
      j2 = p1 ? j1 : (p2 ? j : j2);
      j1 = p0 ? j0 : (p1 ? j : j1);
      j0 = p0 ? j : j0;
      d2 = __builtin_amdgcn_fmed3f(d, d1, d2);
      d1 = __builtin_amdgcn_fmed3f(d, d0, d1);
      d0 = fminf(d, d0);
    }
    d0 = fmaxf(d0, 1e-10f); d1 = fmaxf(d1, 1e-10f); d2 = fmaxf(d2, 1e-10f);
    float w0 = 1.0f / d0, w1 = 1.0f / d1, w2 = 1.0f / d2;
    float ws = w0 + w1 + w2;
    mw[tid * 3 + 0] = w0 / ws; mw[tid * 3 + 1] = w1 / ws; mw[tid * 3 + 2] = w2 / ws;
    mj[tid * 3 + 0] = j0; mj[tid * 3 + 1] = j1; mj[tid * 3 + 2] = j2;
  }
  __syncthreads();

  // staging role: row = tid>>2, 8 cols per thread per step
  int srow = tid >> 2, sh = tid & 3;
  long q = row0 + srow;
  int  b = (int)(q >> 14);  // N1 = 2^14
  float u0 = mw[srow * 3 + 0], u1 = mw[srow * 3 + 1], u2 = mw[srow * 3 + 2];
  const bf16_t* f2bb = f2b_ + (size_t)b * N2 * C2;
  const bf16_t* r0p = f2bb + (size_t)mj[srow * 3 + 0] * C2;
  const bf16_t* r1p = f2bb + (size_t)mj[srow * 3 + 1] * C2;
  const bf16_t* r2p = f2bb + (size_t)mj[srow * 3 + 2] * C2;
  const float* f1r = f1 + (size_t)q * C1;
  bf16_t* asd = As + srow * 32 + sh * 8;
  __syncthreads();  // mw/mj consumed into registers before any Hs reuse

  int wn = wv * 64;
  f32x4 acc[4][4] = {};

  // prefetch ks=0 gather
  bf16x8 g0, g1, g2;
  float4 gfa, gfb;
  {
    int cb = sh * 8;
    g0 = *(const bf16x8*)(r0p + cb);
    g1 = *(const bf16x8*)(r1p + cb);
    g2 = *(const bf16x8*)(r2p + cb);
  }

  for (int ks = 0; ks < 12; ++ks) {
    int kb = ks * 32;
    // W1 stage (verbatim validated pattern: [koct][256 n][8k])
#pragma unroll
    for (int s = 0; s < 4; ++s) {
      __builtin_amdgcn_global_load_lds(
          (const __attribute__((address_space(1))) void*)(
              W1t + (size_t)(wv * 64 + ln) * CIN + kb + s * 8),
          (__attribute__((address_space(3))) void*)(Bs + s * 2048 + wv * 512),
          16, 0, 0);
    }
    // convert prefetched data -> A-tile slab (8 bf16 cols/thread)
    bf16x8 o;
    if (ks < 8) {
#pragma unroll
      for (int e = 0; e < 8; ++e)
        o[e] = (bf16_t)(u0 * (float)g0[e] + u1 * (float)g1[e] + u2 * (float)g2[e]);
    } else {
      o[0] = (bf16_t)gfa.x; o[1] = (bf16_t)gfa.y;
      o[2] = (bf16_t)gfa.z; o[3] = (bf16_t)gfa.w;
      o[4] = (bf16_t)gfb.x; o[5] = (bf16_t)gfb.y;
      o[6] = (bf16_t)gfb.z; o[7] = (bf16_t)gfb.w;
    }
    *(bf16x8*)(asd) = o;
    __syncthreads();

    // prefetch ks+1 (hides under MFMA phase; drained at trailing barrier)
    if (ks < 7) {
      int cb = (ks + 1) * 32 + sh * 8;
      g0 = *(const bf16x8*)(r0p + cb);
      g1 = *(const bf16x8*)(r1p + cb);
      g2 = *(const bf16x8*)(r2p + cb);
    } else if (ks < 11) {
      int cf = (ks - 7) * 32 + sh * 8;
      gfa = *(const float4*)(f1r + cf);
      gfb = *(const float4*)(f1r + cf + 4);
    }

    bf16x8 af[4];
#pragma unroll
    for (int mi = 0; mi < 4; ++mi)
      af[mi] = *(const bf16x8*)(As + (mi * 16 + lm) * 32 + quad * 8);
    bf16x8 bfr[4];
#pragma unroll
    for (int ni = 0; ni < 4; ++ni)
      bfr[ni] = *(const bf16x8*)(Bs + quad * 2048 + (wn + ni * 16 + lm) * 8);
#pragma unroll
    for (int mi = 0; mi < 4; ++mi)
#pragma unroll
      for (int ni = 0; ni < 4; ++ni)
        acc[mi][ni] = __builtin_amdgcn_mfma_f32_16x16x32_bf16(af[mi], bfr[ni],
                                                              acc[mi][ni], 0, 0, 0);
    __syncthreads();
  }

  // ---- epilogue 1: H = relu(acc + b1) -> bf16 -> Hs (XOR-swizzled) ----
#pragma unroll
  for (int mi = 0; mi < 4; ++mi)
#pragma unroll
    for (int ni = 0; ni < 4; ++ni) {
      int col = wn + ni * 16 + lm;      // Hs k-index
      float bv = b1[col];
#pragma unroll
      for (int r = 0; r < 4; ++r) {
        int row = mi * 16 + quad * 4 + r;
        float v = acc[mi][ni][r] + bv;
        v = fmaxf(v, 0.0f);
        int byte = (row * 512 + col * 2) ^ ((row & 7) << 4);
        *(bf16_t*)(hs + byte) = (bf16_t)v;
      }
    }
  __syncthreads();

  // ---- phase 2: out = relu(Hs @ W2t^T + b2) ----
  f32x4 acc2[8] = {};
  for (int k0 = 0; k0 < HD1; k0 += 32) {
    // W2 stage: [koct][128 n][8k], 2 issues x 256 threads x 16B = 8 KB
#pragma unroll
    for (int s = 0; s < 2; ++s) {
      int idx = s * 256 + wv * 64 + ln;
      __builtin_amdgcn_global_load_lds(
          (const __attribute__((address_space(1))) void*)(
              W2t + (size_t)(idx & 127) * HD1 + k0 + (idx >> 7) * 8),
          (__attribute__((address_space(3))) void*)(Bs2 + (s * 256 + wv * 64) * 8),
          16, 0, 0);
    }
    __syncthreads();

    int hrow = wv * 16 + lm;
    bf16x8 af2 = *(const bf16x8*)(
        hs + ((hrow * 512 + (k0 + quad * 8) * 2) ^ ((lm & 7) << 4)));
    bf16x8 bfr2[8];
#pragma unroll
    for (int ni = 0; ni < 8; ++ni)
      bfr2[ni] = *(const bf16x8*)(Bs2 + (quad * 128 + ni * 16 + lm) * 8);
#pragma unroll
    for (int ni = 0; ni < 8; ++ni)
      acc2[ni] = __builtin_amdgcn_mfma_f32_16x16x32_bf16(af2, bfr2[ni],
                                                         acc2[ni], 0, 0, 0);
    __syncthreads();
  }

  // ---- epilogue 2: out (fp32) ----
#pragma unroll
  for (int ni = 0; ni < 8; ++ni) {
    int col = ni * 16 + lm;
    float bv = b2[col];
#pragma unroll
    for (int r = 0; r < 4; ++r) {
      long rowg = row0 + wv * 16 + quad * 4 + r;
      float v = acc2[ni][r] + bv;
      v = fmaxf(v, 0.0f);
      out[rowg * HD2 + col] = v;
    }
  }
}

extern "C" void kernel_launch(void* const* d_in, const int* in_sizes, int n_in,
                              void* d_out, int out_size, void* d_ws, size_t ws_size,
                              hipStream_t stream) {
  const float* xyz1 = (const float*)d_in[0];
  const float* xyz2 = (const float*)d_in[1];
  const float* f1   = (const float*)d_in[2];
  const float* f2   = (const float*)d_in[3];
  const float* W1   = (const float*)d_in[4];
  const float* b1   = (const float*)d_in[5];
  const float* W2   = (const float*)d_in[6];
  const float* b2   = (const float*)d_in[7];
  float* out = (float*)d_out;

  const size_t NQ = (size_t)BDIM * N1;  // 65536
  char* ws = (char*)d_ws;
  bf16_t* W1t  = (bf16_t*)ws;                        // 192 KB
  bf16_t* W2t  = (bf16_t*)(ws + (256 << 10));        // 64 KB
  bf16_t* f2bf = (bf16_t*)(ws + (512 << 10));        // 8.4 MB
  float*  candd = (float*)(ws + (10 << 20));         // 6.3 MB
  int*    candj = (int*)(ws + (17 << 20));           // 6.3 MB

  prep_w<<<dim3(2048), dim3(256), 0, stream>>>(W1, W2, f2, W1t, W2t, f2bf);
  knn_chunk<<<dim3(N1 / 256, BDIM, NCHUNK), dim3(256), 0, stream>>>(
      xyz1, xyz2, candd, candj);
  fused_tail<<<dim3(NQ / 64), dim3(256), 0, stream>>>(
      f1, f2bf, candd, candj, W1t, b1, W2t, b2, out);
}